// Round 25
// baseline (183.940 us; speedup 1.0000x reference)
//
#include <hip/hip_runtime.h>
#include <math.h>

#define IN_DIM 128
#define HID_DIM 256
#define OUT_DIM 128
#define HEADS 4
#define N0 80000
#define N1 40000
#define N2 8000
#define E1 400000
#define E2 128000
#define NEG 0.2f
#define NB1 40
#define NB2 8
#define PAD 16  // ints per degree counter (one 64B line each)
// phase0: zero (N1+N2)*64 B = 192000 float4 -> 750 blocks; + 4 p1 blocks
#define ZERO_BLKS 750
#define PH0_BLKS (ZERO_BLKS + 4)
// phase1 block ranges (r13 ordering: prep, cast, hist). hist: 8 edges/thread.
#define PREP_BLKS 644
#define CAST_BLKS 1250          // N0/64
#define HIST_BLKS 258           // 66048 threads * 8 edges >= E1+E2
#define PH1_BLKS (PREP_BLKS + CAST_BLKS + HIST_BLKS)

typedef __attribute__((ext_vector_type(8))) short bf16x8;
typedef __attribute__((ext_vector_type(4))) float f32x4;

__device__ __forceinline__ float bf2f(short s) {
  return __uint_as_float(((unsigned int)(unsigned short)s) << 16);
}
__device__ __forceinline__ short f2bf(float f) {
  unsigned int u = __float_as_uint(f);
  unsigned int r = (u + 0x7FFFu + ((u >> 16) & 1u)) >> 16;
  return (short)r;
}
__device__ __forceinline__ float lrelu(float t) {
  return t > 0.f ? t : NEG * t;
}

// -------- phase0: zero padded deg1|deg2 ∪ compute p1 ----------------------
__global__ __launch_bounds__(256) void phase0_kernel(
    float4* __restrict__ zp, const float* __restrict__ W1,
    const float* __restrict__ att_s1, const float* __restrict__ att_d1,
    float* __restrict__ p1) {
  int b = blockIdx.x, t = threadIdx.x;
  if (b < ZERO_BLKS) {
    int i = b * 256 + t;
    if (i < (N1 + N2) * 4) zp[i] = make_float4(0.f, 0.f, 0.f, 0.f);
  } else {
    // p1[i][hh] = sum_c W1[i, h*128+c] * att[h][c]
    int g = (b - ZERO_BLKS) * 256 + t;  // 0..1023
    int i = g >> 3, hh = g & 7;
    int h = hh & 3;
    const float* att = (hh < 4) ? att_s1 : att_d1;
    float acc = 0.f;
    for (int c = 0; c < 128; c++)
      acc += W1[(long)i * 512 + h * 128 + c] * att[h * 128 + c];
    p1[g] = acc;
  }
}

// ------- phase1: prep(-p1) ∪ cast+attn1 ∪ hist (all independent) ----------
__global__ __launch_bounds__(256) void phase1_kernel(
    const float* __restrict__ W1, const float* __restrict__ b1,
    const float* __restrict__ c1w, const float* __restrict__ c1b,
    const float* __restrict__ W2, const float* __restrict__ att_s2,
    const float* __restrict__ att_d2, const float* __restrict__ b2,
    const float* __restrict__ c2w, const float* __restrict__ c2b,
    short* __restrict__ M1t, const float* __restrict__ p1,
    float* __restrict__ bias1p, short* __restrict__ M2t,
    float* __restrict__ p2, float* __restrict__ bias2p,
    const float* __restrict__ x, short* __restrict__ x_bf,
    float* __restrict__ a_s, float* __restrict__ a_d,
    const int* __restrict__ ed1, const int* __restrict__ ed2,
    int* __restrict__ deg1, int* __restrict__ deg2, int* __restrict__ rank1,
    int* __restrict__ rank2) {
  int b = blockIdx.x, t = threadIdx.x;
  if (b < PREP_BLKS) {
    if (b < 512) {  // M1t[o][kf] = sum_c W1[k, h*128+c]*c1w[o, h*128+c]
      int g = b * 256 + t;
      int o = g >> 9, kf = g & 511;
      int h = kf >> 7, k = kf & 127;
      float acc = 0.f;
      for (int c = 0; c < 128; c++)
        acc +=
            W1[(long)k * 512 + h * 128 + c] * c1w[(long)o * 512 + h * 128 + c];
      M1t[g] = f2bf(acc);
    } else if (b < 640) {  // M2t[o][k] = sum_c W2[k,c]*c2w[o,c]
      int g = (b - 512) * 256 + t;
      int o = g >> 8, k = g & 255;
      float acc = 0.f;
      for (int c = 0; c < 256; c++)
        acc += W2[(long)k * 256 + c] * c2w[(long)o * 256 + c];
      M2t[g] = f2bf(acc);
    } else if (b == 640) {  // bias1p
      if (t < 256) {
        float acc = c1b[t];
        for (int c = 0; c < 512; c++) acc += b1[c] * c1w[(long)t * 512 + c];
        bias1p[t] = acc;
      }
    } else if (b < 643) {  // p2[k][j]
      int g = (b - 641) * 256 + t;
      if (g < 512) {
        int k = g >> 1, j = g & 1;
        const float* att = j ? att_d2 : att_s2;
        float acc = 0.f;
        for (int c = 0; c < 256; c++) acc += W2[(long)k * 256 + c] * att[c];
        p2[g] = acc;
      }
    } else {  // bias2p
      if (t < 128) {
        float acc = c2b[t];
        for (int c = 0; c < 256; c++) acc += b2[c] * c2w[(long)t * 256 + c];
        bias2p[t] = acc;
      }
    }
  } else if (b < PREP_BLKS + CAST_BLKS) {
    // cast + attn1: 16 lanes per 4-node group; N0 = 1250*64 exact
    int bb = b - PREP_BLKS;
    int l16 = t & 15;
    long nb = ((long)bb * 16 + (t >> 4)) * 4;
    int ch0 = l16 * 8;
    float xs[4][8];
#pragma unroll
    for (int i = 0; i < 4; i++) {
      float4 a = *(const float4*)&x[(nb + i) * 128 + ch0];
      float4 bv = *(const float4*)&x[(nb + i) * 128 + ch0 + 4];
      xs[i][0] = a.x; xs[i][1] = a.y; xs[i][2] = a.z; xs[i][3] = a.w;
      xs[i][4] = bv.x; xs[i][5] = bv.y; xs[i][6] = bv.z; xs[i][7] = bv.w;
    }
#pragma unroll
    for (int i = 0; i < 4; i++) {
      short4 o1, o2;
      o1.x = f2bf(xs[i][0]); o1.y = f2bf(xs[i][1]);
      o1.z = f2bf(xs[i][2]); o1.w = f2bf(xs[i][3]);
      o2.x = f2bf(xs[i][4]); o2.y = f2bf(xs[i][5]);
      o2.z = f2bf(xs[i][6]); o2.w = f2bf(xs[i][7]);
      *(short4*)&x_bf[(nb + i) * 128 + ch0] = o1;
      *(short4*)&x_bf[(nb + i) * 128 + ch0 + 4] = o2;
    }
    float acc[4][8] = {};
#pragma unroll
    for (int c = 0; c < 8; c++) {
      float4 pA = *(const float4*)&p1[(ch0 + c) * 8];
      float4 pB = *(const float4*)&p1[(ch0 + c) * 8 + 4];
#pragma unroll
      for (int i = 0; i < 4; i++) {
        float xc = xs[i][c];
        acc[i][0] += xc * pA.x; acc[i][1] += xc * pA.y;
        acc[i][2] += xc * pA.z; acc[i][3] += xc * pA.w;
        acc[i][4] += xc * pB.x; acc[i][5] += xc * pB.y;
        acc[i][6] += xc * pB.z; acc[i][7] += xc * pB.w;
      }
    }
#pragma unroll
    for (int off = 1; off <= 8; off <<= 1) {
#pragma unroll
      for (int i = 0; i < 4; i++)
#pragma unroll
        for (int k = 0; k < 8; k++) acc[i][k] += __shfl_xor(acc[i][k], off);
    }
    if (l16 == 0) {
#pragma unroll
      for (int i = 0; i < 4; i++) {
        long n = nb + i;
        *(float4*)&a_s[n * 4] =
            make_float4(acc[i][0], acc[i][1], acc[i][2], acc[i][3]);
        if (n < N1)
          *(float4*)&a_d[n * 4] =
              make_float4(acc[i][4], acc[i][5], acc[i][6], acc[i][7]);
      }
    }
  } else {
    // hist: 8 edges per thread (two int4 loads, 8 independent atomics)
    int g = (b - PREP_BLKS - CAST_BLKS) * 256 + t;
    if (g < E1 / 8) {
      long e0 = (long)g * 8;
      int4 da = *(const int4*)&ed1[e0];
      int4 db = *(const int4*)&ed1[e0 + 4];
      int4 ra, rb;
      ra.x = atomicAdd(&deg1[(long)da.x * PAD], 1);
      ra.y = atomicAdd(&deg1[(long)da.y * PAD], 1);
      ra.z = atomicAdd(&deg1[(long)da.z * PAD], 1);
      ra.w = atomicAdd(&deg1[(long)da.w * PAD], 1);
      rb.x = atomicAdd(&deg1[(long)db.x * PAD], 1);
      rb.y = atomicAdd(&deg1[(long)db.y * PAD], 1);
      rb.z = atomicAdd(&deg1[(long)db.z * PAD], 1);
      rb.w = atomicAdd(&deg1[(long)db.w * PAD], 1);
      *(int4*)&rank1[e0] = ra;
      *(int4*)&rank1[e0 + 4] = rb;
    } else if (g < (E1 + E2) / 8) {
      long e0 = (long)(g - E1 / 8) * 8;
      int4 da = *(const int4*)&ed2[e0];
      int4 db = *(const int4*)&ed2[e0 + 4];
      int4 ra, rb;
      ra.x = atomicAdd(&deg2[(long)da.x * PAD], 1);
      ra.y = atomicAdd(&deg2[(long)da.y * PAD], 1);
      ra.z = atomicAdd(&deg2[(long)da.z * PAD], 1);
      ra.w = atomicAdd(&deg2[(long)da.w * PAD], 1);
      rb.x = atomicAdd(&deg2[(long)db.x * PAD], 1);
      rb.y = atomicAdd(&deg2[(long)db.y * PAD], 1);
      rb.z = atomicAdd(&deg2[(long)db.z * PAD], 1);
      rb.w = atomicAdd(&deg2[(long)db.w * PAD], 1);
      *(int4*)&rank2[e0] = ra;
      *(int4*)&rank2[e0 + 4] = rb;
    }
  }
}

// -------- bf16 MFMA GEMM, BK=64: C[M,N] = A[M,K] @ Bt[N,K]^T (+bias) ------
template<bool BIAS, bool OUTBF>
__global__ __launch_bounds__(256) void mm_bf16_kernel(
    const short* __restrict__ A, const short* __restrict__ Bt,
    const float* __restrict__ bias, void* __restrict__ Cv,
    int M, int N, int K) {
  __shared__ short As[128][72];
  __shared__ short Bs[64][72];
  int tid = threadIdx.x;
  int bn = blockIdx.x * 64;
  int bm = blockIdx.y * 128;
  int w = tid >> 6;
  int lane = tid & 63;
  int lr = lane & 15, kb = lane >> 4;
  f32x4 acc[2][4] = {};

  for (int k0 = 0; k0 < K; k0 += 64) {
#pragma unroll
    for (int i = 0; i < 4; i++) {
      int seg = tid + i * 256;
      int row = seg >> 3, part = seg & 7;
      int gm = bm + row;
      bf16x8 v = {0, 0, 0, 0, 0, 0, 0, 0};
      if (gm < M) v = *(const bf16x8*)(A + (long)gm * K + k0 + part * 8);
      *(bf16x8*)&As[row][part * 8] = v;
    }
#pragma unroll
    for (int i = 0; i < 2; i++) {
      int seg = tid + i * 256;
      int r = seg >> 3, part = seg & 7;
      *(bf16x8*)&Bs[r][part * 8] =
          *(const bf16x8*)(Bt + (long)(bn + r) * K + k0 + part * 8);
    }
    __syncthreads();
#pragma unroll
    for (int kk = 0; kk < 64; kk += 32) {
      bf16x8 a0 = *(const bf16x8*)&As[w * 32 + lr][kk + kb * 8];
      bf16x8 a1 = *(const bf16x8*)&As[w * 32 + 16 + lr][kk + kb * 8];
      bf16x8 b0 = *(const bf16x8*)&Bs[lr][kk + kb * 8];
      bf16x8 b1 = *(const bf16x8*)&Bs[16 + lr][kk + kb * 8];
      bf16x8 b2 = *(const bf16x8*)&Bs[32 + lr][kk + kb * 8];
      bf16x8 b3 = *(const bf16x8*)&Bs[48 + lr][kk + kb * 8];
      acc[0][0] = __builtin_amdgcn_mfma_f32_16x16x32_bf16(a0, b0, acc[0][0], 0, 0, 0);
      acc[0][1] = __builtin_amdgcn_mfma_f32_16x16x32_bf16(a0, b1, acc[0][1], 0, 0, 0);
      acc[0][2] = __builtin_amdgcn_mfma_f32_16x16x32_bf16(a0, b2, acc[0][2], 0, 0, 0);
      acc[0][3] = __builtin_amdgcn_mfma_f32_16x16x32_bf16(a0, b3, acc[0][3], 0, 0, 0);
      acc[1][0] = __builtin_amdgcn_mfma_f32_16x16x32_bf16(a1, b0, acc[1][0], 0, 0, 0);
      acc[1][1] = __builtin_amdgcn_mfma_f32_16x16x32_bf16(a1, b1, acc[1][1], 0, 0, 0);
      acc[1][2] = __builtin_amdgcn_mfma_f32_16x16x32_bf16(a1, b2, acc[1][2], 0, 0, 0);
      acc[1][3] = __builtin_amdgcn_mfma_f32_16x16x32_bf16(a1, b3, acc[1][3], 0, 0, 0);
    }
    __syncthreads();
  }
#pragma unroll
  for (int mt = 0; mt < 2; mt++) {
#pragma unroll
    for (int nt = 0; nt < 4; nt++) {
#pragma unroll
      for (int r = 0; r < 4; r++) {
        int row = bm + w * 32 + mt * 16 + kb * 4 + r;
        if (row >= M) continue;
        int col = bn + nt * 16 + lr;
        float v = acc[mt][nt][r];
        if (BIAS) v += bias[col];
        if (OUTBF)
          ((short*)Cv)[(long)row * N + col] = f2bf(v);
        else
          ((float*)Cv)[(long)row * N + col] = v;
      }
    }
  }
}

// ---------- attn2: 32 lanes per node, 2 nodes per wave ----------
__global__ __launch_bounds__(256) void attn2_kernel(
    const short* __restrict__ hid1, const float* __restrict__ p2,
    float* __restrict__ a_s, float* __restrict__ a_d) {
  int tid = threadIdx.x;
  int l32 = tid & 31;
  long n = (long)blockIdx.x * 8 + (tid >> 5);
  if (n >= N1) return;
  int ch0 = l32 * 8;
  bf16x8 hv = *(const bf16x8*)&hid1[n * 256 + ch0];
  float s = 0.f, d = 0.f;
#pragma unroll
  for (int c = 0; c < 8; c += 2) {
    float4 q = *(const float4*)&p2[(ch0 + c) * 2];
    float h0 = bf2f(hv[c]), h1 = bf2f(hv[c + 1]);
    s += h0 * q.x + h1 * q.z;
    d += h0 * q.y + h1 * q.w;
  }
#pragma unroll
  for (int off = 1; off <= 16; off <<= 1) {
    s += __shfl_xor(s, off);
    d += __shfl_xor(d, off);
  }
  if (l32 == 0) {
    a_s[n] = s;
    if (n < N2) a_d[n] = d;
  }
}

// scanA: per-1024-tile sums for both layers (padded counters)
__global__ __launch_bounds__(256) void scanA12_kernel(
    const int* __restrict__ deg1, const int* __restrict__ deg2,
    int* __restrict__ part) {
  __shared__ int red[256];
  int b = blockIdx.x;
  const int* deg;
  int n, base;
  if (b < NB1) { deg = deg1; n = N1; base = b * 1024; }
  else { deg = deg2; n = N2; base = (b - NB1) * 1024; }
  int s = 0;
  for (int i = threadIdx.x; i < 1024; i += 256) {
    int idx = base + i;
    if (idx < n) s += deg[(long)idx * PAD];
  }
  red[threadIdx.x] = s;
  __syncthreads();
  for (int off = 128; off >= 1; off >>= 1) {
    if (threadIdx.x < off) red[threadIdx.x] += red[threadIdx.x + off];
    __syncthreads();
  }
  if (threadIdx.x == 0) part[b] = red[0];
}

// scanC: local scan + inline block-prefix from raw partials (padded)
__global__ __launch_bounds__(256) void scanC12_kernel(
    const int* __restrict__ deg1, const int* __restrict__ deg2,
    const int* __restrict__ part, int* __restrict__ offs1,
    int* __restrict__ offs2) {
  __shared__ int tsum[256];
  int b = blockIdx.x;
  const int* deg;
  int n, pbase, bl;
  int* offs;
  if (b < NB1) { deg = deg1; n = N1; offs = offs1; pbase = 0; bl = b; }
  else { deg = deg2; n = N2; offs = offs2; pbase = NB1; bl = b - NB1; }
  int boff = 0;
  for (int i = 0; i < bl; i++) boff += part[pbase + i];
  int base = bl * 1024;
  int v[4];
  int s = 0;
#pragma unroll
  for (int k = 0; k < 4; k++) {
    int idx = base + threadIdx.x * 4 + k;
    v[k] = (idx < n) ? deg[(long)idx * PAD] : 0;
    s += v[k];
  }
  tsum[threadIdx.x] = s;
  __syncthreads();
  for (int off = 1; off < 256; off <<= 1) {
    int t = (threadIdx.x >= off) ? tsum[threadIdx.x - off] : 0;
    __syncthreads();
    tsum[threadIdx.x] += t;
    __syncthreads();
  }
  int run = boff + ((threadIdx.x > 0) ? tsum[threadIdx.x - 1] : 0);
#pragma unroll
  for (int k = 0; k < 4; k++) {
    int idx = base + threadIdx.x * 4 + k;
    if (idx < n) {
      offs[idx] = run;
      run += v[k];
    }
  }
  if (bl == 0 && threadIdx.x == 0) offs[n] = (b < NB1) ? E1 : E2;
}

// scatter layer1: store exp(logit) per (edge,head); no atomics
__global__ void scatter1_kernel(const int* __restrict__ src,
                                const int* __restrict__ dst, int E,
                                const int* __restrict__ offs,
                                const int* __restrict__ rank,
                                const float* __restrict__ a_s,
                                const float* __restrict__ a_d,
                                int* __restrict__ csr_src,
                                float* __restrict__ csr_w) {
  int e = blockIdx.x * blockDim.x + threadIdx.x;
  if (e >= E) return;
  int s = src[e], d = dst[e];
  int p = offs[d] + rank[e];
  csr_src[p] = s;
  float4 as = *(const float4*)&a_s[s * 4];
  float4 ad = *(const float4*)&a_d[d * 4];
  float4 t;
  t.x = __expf(lrelu(as.x + ad.x));
  t.y = __expf(lrelu(as.y + ad.y));
  t.z = __expf(lrelu(as.z + ad.z));
  t.w = __expf(lrelu(as.w + ad.w));
  *(float4*)&csr_w[(long)p * 4] = t;
}

__global__ void scatter2_kernel(const int* __restrict__ src,
                                const int* __restrict__ dst, int E,
                                const int* __restrict__ offs,
                                const int* __restrict__ rank,
                                const float* __restrict__ a_s,
                                const float* __restrict__ a_d,
                                int* __restrict__ csr_src,
                                float* __restrict__ csr_w) {
  int e = blockIdx.x * blockDim.x + threadIdx.x;
  if (e >= E) return;
  int s = src[e], d = dst[e];
  int p = offs[d] + rank[e];
  csr_src[p] = s;
  csr_w[p] = __expf(lrelu(a_s[s] + a_d[d]));
}

// gather1: wave per node, half-wave per edge stream; denominator in-register
__global__ __launch_bounds__(256) void gather1_kernel(
    const short* __restrict__ x, const int* __restrict__ csr_src,
    const float* __restrict__ csr_w, const int* __restrict__ offs,
    short* __restrict__ z1) {
  int wid = threadIdx.x >> 6, lane = threadIdx.x & 63;
  long d = (long)blockIdx.x * 4 + wid;
  if (d >= N1) return;
  int lo = offs[d], deg = offs[d + 1] - lo;
  int half = lane >> 5, l32 = lane & 31;
  float acc[4][4] = {};
  float den[4] = {};
#pragma unroll 2
  for (int j = half; j < deg; j += 2) {
    long p = lo + j;
    int s = csr_src[p];                              // 32-lane broadcast
    float4 w = *(const float4*)&csr_w[p * 4];        // 32-lane broadcast
    short4 xv = *(const short4*)&x[(long)s * 128 + l32 * 4];
    float f0 = bf2f(xv.x), f1 = bf2f(xv.y), f2 = bf2f(xv.z), f3 = bf2f(xv.w);
    den[0] += w.x; den[1] += w.y; den[2] += w.z; den[3] += w.w;
    acc[0][0] += w.x * f0; acc[0][1] += w.x * f1; acc[0][2] += w.x * f2; acc[0][3] += w.x * f3;
    acc[1][0] += w.y * f0; acc[1][1] += w.y * f1; acc[1][2] += w.y * f2; acc[1][3] += w.y * f3;
    acc[2][0] += w.z * f0; acc[2][1] += w.z * f1; acc[2][2] += w.z * f2; acc[2][3] += w.z * f3;
    acc[3][0] += w.w * f0; acc[3][1] += w.w * f1; acc[3][2] += w.w * f2; acc[3][3] += w.w * f3;
  }
#pragma unroll
  for (int h = 0; h < 4; h++) {
    den[h] += __shfl_xor(den[h], 32);
#pragma unroll
    for (int k = 0; k < 4; k++) acc[h][k] += __shfl_xor(acc[h][k], 32);
  }
  if (half == 0) {
#pragma unroll
    for (int h = 0; h < 4; h++) {
      float inv = 1.f / (den[h] + 1e-16f);
      short4 o;
      o.x = f2bf(acc[h][0] * inv);
      o.y = f2bf(acc[h][1] * inv);
      o.z = f2bf(acc[h][2] * inv);
      o.w = f2bf(acc[h][3] * inv);
      *(short4*)&z1[d * 512 + h * 128 + l32 * 4] = o;
    }
  }
}

// gather2: wave per node, half-wave per edge stream; denominator in-register
__global__ __launch_bounds__(256) void gather2_kernel(
    const short* __restrict__ hid1, const int* __restrict__ csr_src,
    const float* __restrict__ csr_w, const int* __restrict__ offs,
    short* __restrict__ z2) {
  int wid = threadIdx.x >> 6, lane = threadIdx.x & 63;
  long d = (long)blockIdx.x * 4 + wid;
  if (d >= N2) return;
  int lo = offs[d], deg = offs[d + 1] - lo;
  int half = lane >> 5, l32 = lane & 31;
  int ch0 = l32 * 8;
  float acc[8] = {};
  float den = 0.f;
#pragma unroll 2
  for (int j = half; j < deg; j += 2) {
    long p = lo + j;
    int s = csr_src[p];
    float w = csr_w[p];
    den += w;
    bf16x8 v = *(const bf16x8*)&hid1[(long)s * 256 + ch0];
#pragma unroll
    for (int k = 0; k < 8; k++) acc[k] += w * bf2f(v[k]);
  }
  den += __shfl_xor(den, 32);
#pragma unroll
  for (int k = 0; k < 8; k++) acc[k] += __shfl_xor(acc[k], 32);
  if (half == 0) {
    float inv = 1.f / (den + 1e-16f);
    bf16x8 o;
#pragma unroll
    for (int k = 0; k < 8; k++) o[k] = f2bf(acc[k] * inv);
    *(bf16x8*)&z2[d * 256 + ch0] = o;
  }
}

extern "C" void kernel_launch(void* const* d_in, const int* in_sizes, int n_in,
                              void* d_out, int out_size, void* d_ws,
                              size_t ws_size, hipStream_t stream) {
  const float* x = (const float*)d_in[0];
  const int* es1 = (const int*)d_in[1];
  const int* ed1 = (const int*)d_in[2];
  const int* es2 = (const int*)d_in[3];
  const int* ed2 = (const int*)d_in[4];
  const float* W1 = (const float*)d_in[5];
  const float* att_s1 = (const float*)d_in[6];
  const float* att_d1 = (const float*)d_in[7];
  const float* b1 = (const float*)d_in[8];
  const float* W2 = (const float*)d_in[9];
  const float* att_s2 = (const float*)d_in[10];
  const float* att_d2 = (const float*)d_in[11];
  const float* b2 = (const float*)d_in[12];
  const float* c1w = (const float*)d_in[13];
  const float* c1b = (const float*)d_in[14];
  const float* c2w = (const float*)d_in[15];
  const float* c2b = (const float*)d_in[16];
  float* out = (float*)d_out;

  char* ws = (char*)d_ws;
  size_t off = 0;
  auto alloc = [&](size_t bytes) {
    void* p = ws + off;
    off += (bytes + 255) & ~(size_t)255;
    return p;
  };
  short* x_bf = (short*)alloc((size_t)N0 * 128 * 2);
  short* z1 = (short*)alloc((size_t)N1 * 512 * 2);
  short* hid1 = (short*)alloc((size_t)N1 * 256 * 2);
  short* z2 = (short*)alloc((size_t)N2 * 256 * 2);
  float* p1 = (float*)alloc(128 * 8 * 4);
  short* M1t = (short*)alloc(256 * 512 * 2);
  float* bias1p = (float*)alloc(256 * 4);
  float* p2 = (float*)alloc(256 * 2 * 4);
  short* M2t = (short*)alloc(128 * 256 * 2);
  float* bias2p = (float*)alloc(128 * 4);
  float* as1 = (float*)alloc((size_t)N0 * 4 * 4);
  float* ad1v = (float*)alloc((size_t)N1 * 4 * 4);
  float* as2 = (float*)alloc((size_t)N1 * 4);
  float* ad2v = (float*)alloc((size_t)N2 * 4);
  int* deg1 = (int*)alloc((size_t)N1 * PAD * 4);  // padded: 64B per counter
  int* deg2 = (int*)alloc((size_t)N2 * PAD * 4);  // adjacent to deg1
  int* offs1 = (int*)alloc((size_t)(N1 + 1) * 4);
  int* rank1 = (int*)alloc((size_t)E1 * 4);
  int* offs2 = (int*)alloc((size_t)(N2 + 1) * 4);
  int* rank2 = (int*)alloc((size_t)E2 * 4);
  int* part12 = (int*)alloc(64 * 4);
  int* csr_src1 = (int*)alloc((size_t)E1 * 4);
  float* csr_w1 = (float*)alloc((size_t)E1 * 4 * 4);
  int* csr_src2 = (int*)alloc((size_t)E2 * 4);
  float* csr_w2 = (float*)alloc((size_t)E2 * 4);

  // phase0: zero padded deg1|deg2 ∪ compute p1
  phase0_kernel<<<PH0_BLKS, 256, 0, stream>>>((float4*)deg1, W1, att_s1,
                                              att_d1, p1);

  // phase1: prep(-p1) ∪ cast+attn1 ∪ hist — one dispatch (r13 ordering)
  phase1_kernel<<<PH1_BLKS, 256, 0, stream>>>(
      W1, b1, c1w, c1b, W2, att_s2, att_d2, b2, c2w, c2b, M1t, p1, bias1p,
      M2t, p2, bias2p, x, x_bf, as1, ad1v, ed1, ed2, deg1, deg2, rank1, rank2);

  scanA12_kernel<<<NB1 + NB2, 256, 0, stream>>>(deg1, deg2, part12);
  scanC12_kernel<<<NB1 + NB2, 256, 0, stream>>>(deg1, deg2, part12, offs1,
                                                offs2);
  scatter1_kernel<<<(E1 + 255) / 256, 256, 0, stream>>>(
      es1, ed1, E1, offs1, rank1, as1, ad1v, csr_src1, csr_w1);
  gather1_kernel<<<(N1 + 3) / 4, 256, 0, stream>>>(x_bf, csr_src1, csr_w1,
                                                   offs1, z1);
  mm_bf16_kernel<true, true><<<dim3(4, (N1 + 127) / 128), 256, 0, stream>>>(
      z1, M1t, bias1p, hid1, N1, 256, 512);

  attn2_kernel<<<(N1 + 7) / 8, 256, 0, stream>>>(hid1, p2, as2, ad2v);
  scatter2_kernel<<<(E2 + 255) / 256, 256, 0, stream>>>(
      es2, ed2, E2, offs2, rank2, as2, ad2v, csr_src2, csr_w2);
  gather2_kernel<<<(N2 + 3) / 4, 256, 0, stream>>>(hid1, csr_src2, csr_w2,
                                                   offs2, z2);
  mm_bf16_kernel<true, false><<<dim3(2, (N2 + 127) / 128), 256, 0, stream>>>(
      z2, M2t, bias2p, out, N2, 128, 256);
}

// Round 26
// 179.842 us; speedup vs baseline: 1.0228x; 1.0228x over previous
//
#include <hip/hip_runtime.h>
#include <math.h>

#define IN_DIM 128
#define HID_DIM 256
#define OUT_DIM 128
#define HEADS 4
#define N0 80000
#define N1 40000
#define N2 8000
#define E1 400000
#define E2 128000
#define NEG 0.2f
#define NB1 40
#define NB2 8
#define PAD 16  // ints per degree counter (one 64B line each)
// phase0: zero (N1+N2)*64 B = 192000 float4 -> 750 blocks; + 4 p1 blocks
#define ZERO_BLKS 750
#define PH0_BLKS (ZERO_BLKS + 4)
// phase1 block ranges (r13 ordering: prep, cast, hist). hist: 8 edges/thread.
#define PREP_BLKS 644
#define CAST_BLKS 1250          // N0/64
#define HIST_BLKS 258           // 66048 threads * 8 edges >= E1+E2
#define PH1_BLKS (PREP_BLKS + CAST_BLKS + HIST_BLKS)

typedef __attribute__((ext_vector_type(8))) short bf16x8;
typedef __attribute__((ext_vector_type(4))) float f32x4;

__device__ __forceinline__ float bf2f(short s) {
  return __uint_as_float(((unsigned int)(unsigned short)s) << 16);
}
__device__ __forceinline__ short f2bf(float f) {
  unsigned int u = __float_as_uint(f);
  unsigned int r = (u + 0x7FFFu + ((u >> 16) & 1u)) >> 16;
  return (short)r;
}
__device__ __forceinline__ float lrelu(float t) {
  return t > 0.f ? t : NEG * t;
}

// -------- phase0: zero padded deg1|deg2 ∪ compute p1 ----------------------
__global__ __launch_bounds__(256) void phase0_kernel(
    float4* __restrict__ zp, const float* __restrict__ W1,
    const float* __restrict__ att_s1, const float* __restrict__ att_d1,
    float* __restrict__ p1) {
  int b = blockIdx.x, t = threadIdx.x;
  if (b < ZERO_BLKS) {
    int i = b * 256 + t;
    if (i < (N1 + N2) * 4) zp[i] = make_float4(0.f, 0.f, 0.f, 0.f);
  } else {
    // p1[i][hh] = sum_c W1[i, h*128+c] * att[h][c]
    int g = (b - ZERO_BLKS) * 256 + t;  // 0..1023
    int i = g >> 3, hh = g & 7;
    int h = hh & 3;
    const float* att = (hh < 4) ? att_s1 : att_d1;
    float acc = 0.f;
    for (int c = 0; c < 128; c++)
      acc += W1[(long)i * 512 + h * 128 + c] * att[h * 128 + c];
    p1[g] = acc;
  }
}

// ------- phase1: prep(-p1) ∪ cast+attn1 ∪ hist (all independent) ----------
__global__ __launch_bounds__(256) void phase1_kernel(
    const float* __restrict__ W1, const float* __restrict__ b1,
    const float* __restrict__ c1w, const float* __restrict__ c1b,
    const float* __restrict__ W2, const float* __restrict__ att_s2,
    const float* __restrict__ att_d2, const float* __restrict__ b2,
    const float* __restrict__ c2w, const float* __restrict__ c2b,
    short* __restrict__ M1t, const float* __restrict__ p1,
    float* __restrict__ bias1p, short* __restrict__ M2t,
    float* __restrict__ p2, float* __restrict__ bias2p,
    const float* __restrict__ x, short* __restrict__ x_bf,
    float* __restrict__ a_s, float* __restrict__ a_d,
    const int* __restrict__ ed1, const int* __restrict__ ed2,
    int* __restrict__ deg1, int* __restrict__ deg2, int* __restrict__ rank1,
    int* __restrict__ rank2) {
  int b = blockIdx.x, t = threadIdx.x;
  if (b < PREP_BLKS) {
    if (b < 512) {  // M1t[o][kf] = sum_c W1[k, h*128+c]*c1w[o, h*128+c]
      int g = b * 256 + t;
      int o = g >> 9, kf = g & 511;
      int h = kf >> 7, k = kf & 127;
      float acc = 0.f;
      for (int c = 0; c < 128; c++)
        acc +=
            W1[(long)k * 512 + h * 128 + c] * c1w[(long)o * 512 + h * 128 + c];
      M1t[g] = f2bf(acc);
    } else if (b < 640) {  // M2t[o][k] = sum_c W2[k,c]*c2w[o,c]
      int g = (b - 512) * 256 + t;
      int o = g >> 8, k = g & 255;
      float acc = 0.f;
      for (int c = 0; c < 256; c++)
        acc += W2[(long)k * 256 + c] * c2w[(long)o * 256 + c];
      M2t[g] = f2bf(acc);
    } else if (b == 640) {  // bias1p
      if (t < 256) {
        float acc = c1b[t];
        for (int c = 0; c < 512; c++) acc += b1[c] * c1w[(long)t * 512 + c];
        bias1p[t] = acc;
      }
    } else if (b < 643) {  // p2[k][j]
      int g = (b - 641) * 256 + t;
      if (g < 512) {
        int k = g >> 1, j = g & 1;
        const float* att = j ? att_d2 : att_s2;
        float acc = 0.f;
        for (int c = 0; c < 256; c++) acc += W2[(long)k * 256 + c] * att[c];
        p2[g] = acc;
      }
    } else {  // bias2p
      if (t < 128) {
        float acc = c2b[t];
        for (int c = 0; c < 256; c++) acc += b2[c] * c2w[(long)t * 256 + c];
        bias2p[t] = acc;
      }
    }
  } else if (b < PREP_BLKS + CAST_BLKS) {
    // cast + attn1: 16 lanes per 4-node group; N0 = 1250*64 exact
    int bb = b - PREP_BLKS;
    int l16 = t & 15;
    long nb = ((long)bb * 16 + (t >> 4)) * 4;
    int ch0 = l16 * 8;
    float xs[4][8];
#pragma unroll
    for (int i = 0; i < 4; i++) {
      float4 a = *(const float4*)&x[(nb + i) * 128 + ch0];
      float4 bv = *(const float4*)&x[(nb + i) * 128 + ch0 + 4];
      xs[i][0] = a.x; xs[i][1] = a.y; xs[i][2] = a.z; xs[i][3] = a.w;
      xs[i][4] = bv.x; xs[i][5] = bv.y; xs[i][6] = bv.z; xs[i][7] = bv.w;
    }
#pragma unroll
    for (int i = 0; i < 4; i++) {
      short4 o1, o2;
      o1.x = f2bf(xs[i][0]); o1.y = f2bf(xs[i][1]);
      o1.z = f2bf(xs[i][2]); o1.w = f2bf(xs[i][3]);
      o2.x = f2bf(xs[i][4]); o2.y = f2bf(xs[i][5]);
      o2.z = f2bf(xs[i][6]); o2.w = f2bf(xs[i][7]);
      *(short4*)&x_bf[(nb + i) * 128 + ch0] = o1;
      *(short4*)&x_bf[(nb + i) * 128 + ch0 + 4] = o2;
    }
    float acc[4][8] = {};
#pragma unroll
    for (int c = 0; c < 8; c++) {
      float4 pA = *(const float4*)&p1[(ch0 + c) * 8];
      float4 pB = *(const float4*)&p1[(ch0 + c) * 8 + 4];
#pragma unroll
      for (int i = 0; i < 4; i++) {
        float xc = xs[i][c];
        acc[i][0] += xc * pA.x; acc[i][1] += xc * pA.y;
        acc[i][2] += xc * pA.z; acc[i][3] += xc * pA.w;
        acc[i][4] += xc * pB.x; acc[i][5] += xc * pB.y;
        acc[i][6] += xc * pB.z; acc[i][7] += xc * pB.w;
      }
    }
#pragma unroll
    for (int off = 1; off <= 8; off <<= 1) {
#pragma unroll
      for (int i = 0; i < 4; i++)
#pragma unroll
        for (int k = 0; k < 8; k++) acc[i][k] += __shfl_xor(acc[i][k], off);
    }
    if (l16 == 0) {
#pragma unroll
      for (int i = 0; i < 4; i++) {
        long n = nb + i;
        *(float4*)&a_s[n * 4] =
            make_float4(acc[i][0], acc[i][1], acc[i][2], acc[i][3]);
        if (n < N1)
          *(float4*)&a_d[n * 4] =
              make_float4(acc[i][4], acc[i][5], acc[i][6], acc[i][7]);
      }
    }
  } else {
    // hist: 8 edges per thread (two int4 loads, 8 independent atomics)
    int g = (b - PREP_BLKS - CAST_BLKS) * 256 + t;
    if (g < E1 / 8) {
      long e0 = (long)g * 8;
      int4 da = *(const int4*)&ed1[e0];
      int4 db = *(const int4*)&ed1[e0 + 4];
      int4 ra, rb;
      ra.x = atomicAdd(&deg1[(long)da.x * PAD], 1);
      ra.y = atomicAdd(&deg1[(long)da.y * PAD], 1);
      ra.z = atomicAdd(&deg1[(long)da.z * PAD], 1);
      ra.w = atomicAdd(&deg1[(long)da.w * PAD], 1);
      rb.x = atomicAdd(&deg1[(long)db.x * PAD], 1);
      rb.y = atomicAdd(&deg1[(long)db.y * PAD], 1);
      rb.z = atomicAdd(&deg1[(long)db.z * PAD], 1);
      rb.w = atomicAdd(&deg1[(long)db.w * PAD], 1);
      *(int4*)&rank1[e0] = ra;
      *(int4*)&rank1[e0 + 4] = rb;
    } else if (g < (E1 + E2) / 8) {
      long e0 = (long)(g - E1 / 8) * 8;
      int4 da = *(const int4*)&ed2[e0];
      int4 db = *(const int4*)&ed2[e0 + 4];
      int4 ra, rb;
      ra.x = atomicAdd(&deg2[(long)da.x * PAD], 1);
      ra.y = atomicAdd(&deg2[(long)da.y * PAD], 1);
      ra.z = atomicAdd(&deg2[(long)da.z * PAD], 1);
      ra.w = atomicAdd(&deg2[(long)da.w * PAD], 1);
      rb.x = atomicAdd(&deg2[(long)db.x * PAD], 1);
      rb.y = atomicAdd(&deg2[(long)db.y * PAD], 1);
      rb.z = atomicAdd(&deg2[(long)db.z * PAD], 1);
      rb.w = atomicAdd(&deg2[(long)db.w * PAD], 1);
      *(int4*)&rank2[e0] = ra;
      *(int4*)&rank2[e0 + 4] = rb;
    }
  }
}

// ---- bf16 MFMA GEMM, 128x128 tile, BK=64 (for GEMM1): C = A @ Bt^T + bias
// A bf16 [M,K], Bt bf16 [N,K]; N mult of 128, K mult of 64; bf16 out.
__global__ __launch_bounds__(256) void mm128_bf16_kernel(
    const short* __restrict__ A, const short* __restrict__ Bt,
    const float* __restrict__ bias, short* __restrict__ C,
    int M, int N, int K) {
  __shared__ short As[128][72];
  __shared__ short Bs[128][72];
  int tid = threadIdx.x;
  int bn = blockIdx.x * 128;
  int bm = blockIdx.y * 128;
  int w = tid >> 6;
  int lane = tid & 63;
  int lr = lane & 15, kb = lane >> 4;
  f32x4 acc[2][8] = {};

  for (int k0 = 0; k0 < K; k0 += 64) {
    // stage A: 128x64 bf16 = 1024 segs of 8; 4 per thread
#pragma unroll
    for (int i = 0; i < 4; i++) {
      int seg = tid + i * 256;
      int row = seg >> 3, part = seg & 7;
      int gm = bm + row;
      bf16x8 v = {0, 0, 0, 0, 0, 0, 0, 0};
      if (gm < M) v = *(const bf16x8*)(A + (long)gm * K + k0 + part * 8);
      *(bf16x8*)&As[row][part * 8] = v;
    }
    // stage B: 128x64 bf16 = 1024 segs; 4 per thread
#pragma unroll
    for (int i = 0; i < 4; i++) {
      int seg = tid + i * 256;
      int r = seg >> 3, part = seg & 7;
      *(bf16x8*)&Bs[r][part * 8] =
          *(const bf16x8*)(Bt + (long)(bn + r) * K + k0 + part * 8);
    }
    __syncthreads();
#pragma unroll
    for (int kk = 0; kk < 64; kk += 32) {
      bf16x8 a0 = *(const bf16x8*)&As[w * 32 + lr][kk + kb * 8];
      bf16x8 a1 = *(const bf16x8*)&As[w * 32 + 16 + lr][kk + kb * 8];
#pragma unroll
      for (int nt = 0; nt < 8; nt++) {
        bf16x8 bv = *(const bf16x8*)&Bs[nt * 16 + lr][kk + kb * 8];
        acc[0][nt] =
            __builtin_amdgcn_mfma_f32_16x16x32_bf16(a0, bv, acc[0][nt], 0, 0, 0);
        acc[1][nt] =
            __builtin_amdgcn_mfma_f32_16x16x32_bf16(a1, bv, acc[1][nt], 0, 0, 0);
      }
    }
    __syncthreads();
  }
#pragma unroll
  for (int mt = 0; mt < 2; mt++) {
#pragma unroll
    for (int nt = 0; nt < 8; nt++) {
#pragma unroll
      for (int r = 0; r < 4; r++) {
        int row = bm + w * 32 + mt * 16 + kb * 4 + r;
        if (row >= M) continue;
        int col = bn + nt * 16 + lr;
        C[(long)row * N + col] = f2bf(acc[mt][nt][r] + bias[col]);
      }
    }
  }
}

// -------- bf16 MFMA GEMM, 128x64 tile, BK=64 (for GEMM2, f32 out) ---------
template<bool BIAS, bool OUTBF>
__global__ __launch_bounds__(256) void mm_bf16_kernel(
    const short* __restrict__ A, const short* __restrict__ Bt,
    const float* __restrict__ bias, void* __restrict__ Cv,
    int M, int N, int K) {
  __shared__ short As[128][72];
  __shared__ short Bs[64][72];
  int tid = threadIdx.x;
  int bn = blockIdx.x * 64;
  int bm = blockIdx.y * 128;
  int w = tid >> 6;
  int lane = tid & 63;
  int lr = lane & 15, kb = lane >> 4;
  f32x4 acc[2][4] = {};

  for (int k0 = 0; k0 < K; k0 += 64) {
#pragma unroll
    for (int i = 0; i < 4; i++) {
      int seg = tid + i * 256;
      int row = seg >> 3, part = seg & 7;
      int gm = bm + row;
      bf16x8 v = {0, 0, 0, 0, 0, 0, 0, 0};
      if (gm < M) v = *(const bf16x8*)(A + (long)gm * K + k0 + part * 8);
      *(bf16x8*)&As[row][part * 8] = v;
    }
#pragma unroll
    for (int i = 0; i < 2; i++) {
      int seg = tid + i * 256;
      int r = seg >> 3, part = seg & 7;
      *(bf16x8*)&Bs[r][part * 8] =
          *(const bf16x8*)(Bt + (long)(bn + r) * K + k0 + part * 8);
    }
    __syncthreads();
#pragma unroll
    for (int kk = 0; kk < 64; kk += 32) {
      bf16x8 a0 = *(const bf16x8*)&As[w * 32 + lr][kk + kb * 8];
      bf16x8 a1 = *(const bf16x8*)&As[w * 32 + 16 + lr][kk + kb * 8];
      bf16x8 b0 = *(const bf16x8*)&Bs[lr][kk + kb * 8];
      bf16x8 b1 = *(const bf16x8*)&Bs[16 + lr][kk + kb * 8];
      bf16x8 b2 = *(const bf16x8*)&Bs[32 + lr][kk + kb * 8];
      bf16x8 b3 = *(const bf16x8*)&Bs[48 + lr][kk + kb * 8];
      acc[0][0] = __builtin_amdgcn_mfma_f32_16x16x32_bf16(a0, b0, acc[0][0], 0, 0, 0);
      acc[0][1] = __builtin_amdgcn_mfma_f32_16x16x32_bf16(a0, b1, acc[0][1], 0, 0, 0);
      acc[0][2] = __builtin_amdgcn_mfma_f32_16x16x32_bf16(a0, b2, acc[0][2], 0, 0, 0);
      acc[0][3] = __builtin_amdgcn_mfma_f32_16x16x32_bf16(a0, b3, acc[0][3], 0, 0, 0);
      acc[1][0] = __builtin_amdgcn_mfma_f32_16x16x32_bf16(a1, b0, acc[1][0], 0, 0, 0);
      acc[1][1] = __builtin_amdgcn_mfma_f32_16x16x32_bf16(a1, b1, acc[1][1], 0, 0, 0);
      acc[1][2] = __builtin_amdgcn_mfma_f32_16x16x32_bf16(a1, b2, acc[1][2], 0, 0, 0);
      acc[1][3] = __builtin_amdgcn_mfma_f32_16x16x32_bf16(a1, b3, acc[1][3], 0, 0, 0);
    }
    __syncthreads();
  }
#pragma unroll
  for (int mt = 0; mt < 2; mt++) {
#pragma unroll
    for (int nt = 0; nt < 4; nt++) {
#pragma unroll
      for (int r = 0; r < 4; r++) {
        int row = bm + w * 32 + mt * 16 + kb * 4 + r;
        if (row >= M) continue;
        int col = bn + nt * 16 + lr;
        float v = acc[mt][nt][r];
        if (BIAS) v += bias[col];
        if (OUTBF)
          ((short*)Cv)[(long)row * N + col] = f2bf(v);
        else
          ((float*)Cv)[(long)row * N + col] = v;
      }
    }
  }
}

// ---------- attn2: 32 lanes per node, 2 nodes per wave ----------
__global__ __launch_bounds__(256) void attn2_kernel(
    const short* __restrict__ hid1, const float* __restrict__ p2,
    float* __restrict__ a_s, float* __restrict__ a_d) {
  int tid = threadIdx.x;
  int l32 = tid & 31;
  long n = (long)blockIdx.x * 8 + (tid >> 5);
  if (n >= N1) return;
  int ch0 = l32 * 8;
  bf16x8 hv = *(const bf16x8*)&hid1[n * 256 + ch0];
  float s = 0.f, d = 0.f;
#pragma unroll
  for (int c = 0; c < 8; c += 2) {
    float4 q = *(const float4*)&p2[(ch0 + c) * 2];
    float h0 = bf2f(hv[c]), h1 = bf2f(hv[c + 1]);
    s += h0 * q.x + h1 * q.z;
    d += h0 * q.y + h1 * q.w;
  }
#pragma unroll
  for (int off = 1; off <= 16; off <<= 1) {
    s += __shfl_xor(s, off);
    d += __shfl_xor(d, off);
  }
  if (l32 == 0) {
    a_s[n] = s;
    if (n < N2) a_d[n] = d;
  }
}

// scanA: per-1024-tile sums for both layers (padded counters)
__global__ __launch_bounds__(256) void scanA12_kernel(
    const int* __restrict__ deg1, const int* __restrict__ deg2,
    int* __restrict__ part) {
  __shared__ int red[256];
  int b = blockIdx.x;
  const int* deg;
  int n, base;
  if (b < NB1) { deg = deg1; n = N1; base = b * 1024; }
  else { deg = deg2; n = N2; base = (b - NB1) * 1024; }
  int s = 0;
  for (int i = threadIdx.x; i < 1024; i += 256) {
    int idx = base + i;
    if (idx < n) s += deg[(long)idx * PAD];
  }
  red[threadIdx.x] = s;
  __syncthreads();
  for (int off = 128; off >= 1; off >>= 1) {
    if (threadIdx.x < off) red[threadIdx.x] += red[threadIdx.x + off];
    __syncthreads();
  }
  if (threadIdx.x == 0) part[b] = red[0];
}

// scanC: local scan + inline block-prefix from raw partials (padded)
__global__ __launch_bounds__(256) void scanC12_kernel(
    const int* __restrict__ deg1, const int* __restrict__ deg2,
    const int* __restrict__ part, int* __restrict__ offs1,
    int* __restrict__ offs2) {
  __shared__ int tsum[256];
  int b = blockIdx.x;
  const int* deg;
  int n, pbase, bl;
  int* offs;
  if (b < NB1) { deg = deg1; n = N1; offs = offs1; pbase = 0; bl = b; }
  else { deg = deg2; n = N2; offs = offs2; pbase = NB1; bl = b - NB1; }
  int boff = 0;
  for (int i = 0; i < bl; i++) boff += part[pbase + i];
  int base = bl * 1024;
  int v[4];
  int s = 0;
#pragma unroll
  for (int k = 0; k < 4; k++) {
    int idx = base + threadIdx.x * 4 + k;
    v[k] = (idx < n) ? deg[(long)idx * PAD] : 0;
    s += v[k];
  }
  tsum[threadIdx.x] = s;
  __syncthreads();
  for (int off = 1; off < 256; off <<= 1) {
    int t = (threadIdx.x >= off) ? tsum[threadIdx.x - off] : 0;
    __syncthreads();
    tsum[threadIdx.x] += t;
    __syncthreads();
  }
  int run = boff + ((threadIdx.x > 0) ? tsum[threadIdx.x - 1] : 0);
#pragma unroll
  for (int k = 0; k < 4; k++) {
    int idx = base + threadIdx.x * 4 + k;
    if (idx < n) {
      offs[idx] = run;
      run += v[k];
    }
  }
  if (bl == 0 && threadIdx.x == 0) offs[n] = (b < NB1) ? E1 : E2;
}

// scatter layer1: store exp(logit) per (edge,head); no atomics
__global__ void scatter1_kernel(const int* __restrict__ src,
                                const int* __restrict__ dst, int E,
                                const int* __restrict__ offs,
                                const int* __restrict__ rank,
                                const float* __restrict__ a_s,
                                const float* __restrict__ a_d,
                                int* __restrict__ csr_src,
                                float* __restrict__ csr_w) {
  int e = blockIdx.x * blockDim.x + threadIdx.x;
  if (e >= E) return;
  int s = src[e], d = dst[e];
  int p = offs[d] + rank[e];
  csr_src[p] = s;
  float4 as = *(const float4*)&a_s[s * 4];
  float4 ad = *(const float4*)&a_d[d * 4];
  float4 t;
  t.x = __expf(lrelu(as.x + ad.x));
  t.y = __expf(lrelu(as.y + ad.y));
  t.z = __expf(lrelu(as.z + ad.z));
  t.w = __expf(lrelu(as.w + ad.w));
  *(float4*)&csr_w[(long)p * 4] = t;
}

__global__ void scatter2_kernel(const int* __restrict__ src,
                                const int* __restrict__ dst, int E,
                                const int* __restrict__ offs,
                                const int* __restrict__ rank,
                                const float* __restrict__ a_s,
                                const float* __restrict__ a_d,
                                int* __restrict__ csr_src,
                                float* __restrict__ csr_w) {
  int e = blockIdx.x * blockDim.x + threadIdx.x;
  if (e >= E) return;
  int s = src[e], d = dst[e];
  int p = offs[d] + rank[e];
  csr_src[p] = s;
  csr_w[p] = __expf(lrelu(a_s[s] + a_d[d]));
}

// gather1: wave per node, half-wave per edge stream; denominator in-register
__global__ __launch_bounds__(256) void gather1_kernel(
    const short* __restrict__ x, const int* __restrict__ csr_src,
    const float* __restrict__ csr_w, const int* __restrict__ offs,
    short* __restrict__ z1) {
  int wid = threadIdx.x >> 6, lane = threadIdx.x & 63;
  long d = (long)blockIdx.x * 4 + wid;
  if (d >= N1) return;
  int lo = offs[d], deg = offs[d + 1] - lo;
  int half = lane >> 5, l32 = lane & 31;
  float acc[4][4] = {};
  float den[4] = {};
#pragma unroll 2
  for (int j = half; j < deg; j += 2) {
    long p = lo + j;
    int s = csr_src[p];                              // 32-lane broadcast
    float4 w = *(const float4*)&csr_w[p * 4];        // 32-lane broadcast
    short4 xv = *(const short4*)&x[(long)s * 128 + l32 * 4];
    float f0 = bf2f(xv.x), f1 = bf2f(xv.y), f2 = bf2f(xv.z), f3 = bf2f(xv.w);
    den[0] += w.x; den[1] += w.y; den[2] += w.z; den[3] += w.w;
    acc[0][0] += w.x * f0; acc[0][1] += w.x * f1; acc[0][2] += w.x * f2; acc[0][3] += w.x * f3;
    acc[1][0] += w.y * f0; acc[1][1] += w.y * f1; acc[1][2] += w.y * f2; acc[1][3] += w.y * f3;
    acc[2][0] += w.z * f0; acc[2][1] += w.z * f1; acc[2][2] += w.z * f2; acc[2][3] += w.z * f3;
    acc[3][0] += w.w * f0; acc[3][1] += w.w * f1; acc[3][2] += w.w * f2; acc[3][3] += w.w * f3;
  }
#pragma unroll
  for (int h = 0; h < 4; h++) {
    den[h] += __shfl_xor(den[h], 32);
#pragma unroll
    for (int k = 0; k < 4; k++) acc[h][k] += __shfl_xor(acc[h][k], 32);
  }
  if (half == 0) {
#pragma unroll
    for (int h = 0; h < 4; h++) {
      float inv = 1.f / (den[h] + 1e-16f);
      short4 o;
      o.x = f2bf(acc[h][0] * inv);
      o.y = f2bf(acc[h][1] * inv);
      o.z = f2bf(acc[h][2] * inv);
      o.w = f2bf(acc[h][3] * inv);
      *(short4*)&z1[d * 512 + h * 128 + l32 * 4] = o;
    }
  }
}

// gather2: wave per node, half-wave per edge stream; denominator in-register
__global__ __launch_bounds__(256) void gather2_kernel(
    const short* __restrict__ hid1, const int* __restrict__ csr_src,
    const float* __restrict__ csr_w, const int* __restrict__ offs,
    short* __restrict__ z2) {
  int wid = threadIdx.x >> 6, lane = threadIdx.x & 63;
  long d = (long)blockIdx.x * 4 + wid;
  if (d >= N2) return;
  int lo = offs[d], deg = offs[d + 1] - lo;
  int half = lane >> 5, l32 = lane & 31;
  int ch0 = l32 * 8;
  float acc[8] = {};
  float den = 0.f;
#pragma unroll 2
  for (int j = half; j < deg; j += 2) {
    long p = lo + j;
    int s = csr_src[p];
    float w = csr_w[p];
    den += w;
    bf16x8 v = *(const bf16x8*)&hid1[(long)s * 256 + ch0];
#pragma unroll
    for (int k = 0; k < 8; k++) acc[k] += w * bf2f(v[k]);
  }
  den += __shfl_xor(den, 32);
#pragma unroll
  for (int k = 0; k < 8; k++) acc[k] += __shfl_xor(acc[k], 32);
  if (half == 0) {
    float inv = 1.f / (den + 1e-16f);
    bf16x8 o;
#pragma unroll
    for (int k = 0; k < 8; k++) o[k] = f2bf(acc[k] * inv);
    *(bf16x8*)&z2[d * 256 + ch0] = o;
  }
}

extern "C" void kernel_launch(void* const* d_in, const int* in_sizes, int n_in,
                              void* d_out, int out_size, void* d_ws,
                              size_t ws_size, hipStream_t stream) {
  const float* x = (const float*)d_in[0];
  const int* es1 = (const int*)d_in[1];
  const int* ed1 = (const int*)d_in[2];
  const int* es2 = (const int*)d_in[3];
  const int* ed2 = (const int*)d_in[4];
  const float* W1 = (const float*)d_in[5];
  const float* att_s1 = (const float*)d_in[6];
  const float* att_d1 = (const float*)d_in[7];
  const float* b1 = (const float*)d_in[8];
  const float* W2 = (const float*)d_in[9];
  const float* att_s2 = (const float*)d_in[10];
  const float* att_d2 = (const float*)d_in[11];
  const float* b2 = (const float*)d_in[12];
  const float* c1w = (const float*)d_in[13];
  const float* c1b = (const float*)d_in[14];
  const float* c2w = (const float*)d_in[15];
  const float* c2b = (const float*)d_in[16];
  float* out = (float*)d_out;

  char* ws = (char*)d_ws;
  size_t off = 0;
  auto alloc = [&](size_t bytes) {
    void* p = ws + off;
    off += (bytes + 255) & ~(size_t)255;
    return p;
  };
  short* x_bf = (short*)alloc((size_t)N0 * 128 * 2);
  short* z1 = (short*)alloc((size_t)N1 * 512 * 2);
  short* hid1 = (short*)alloc((size_t)N1 * 256 * 2);
  short* z2 = (short*)alloc((size_t)N2 * 256 * 2);
  float* p1 = (float*)alloc(128 * 8 * 4);
  short* M1t = (short*)alloc(256 * 512 * 2);
  float* bias1p = (float*)alloc(256 * 4);
  float* p2 = (float*)alloc(256 * 2 * 4);
  short* M2t = (short*)alloc(128 * 256 * 2);
  float* bias2p = (float*)alloc(128 * 4);
  float* as1 = (float*)alloc((size_t)N0 * 4 * 4);
  float* ad1v = (float*)alloc((size_t)N1 * 4 * 4);
  float* as2 = (float*)alloc((size_t)N1 * 4);
  float* ad2v = (float*)alloc((size_t)N2 * 4);
  int* deg1 = (int*)alloc((size_t)N1 * PAD * 4);  // padded: 64B per counter
  int* deg2 = (int*)alloc((size_t)N2 * PAD * 4);  // adjacent to deg1
  int* offs1 = (int*)alloc((size_t)(N1 + 1) * 4);
  int* rank1 = (int*)alloc((size_t)E1 * 4);
  int* offs2 = (int*)alloc((size_t)(N2 + 1) * 4);
  int* rank2 = (int*)alloc((size_t)E2 * 4);
  int* part12 = (int*)alloc(64 * 4);
  int* csr_src1 = (int*)alloc((size_t)E1 * 4);
  float* csr_w1 = (float*)alloc((size_t)E1 * 4 * 4);
  int* csr_src2 = (int*)alloc((size_t)E2 * 4);
  float* csr_w2 = (float*)alloc((size_t)E2 * 4);

  // phase0: zero padded deg1|deg2 ∪ compute p1
  phase0_kernel<<<PH0_BLKS, 256, 0, stream>>>((float4*)deg1, W1, att_s1,
                                              att_d1, p1);

  // phase1: prep(-p1) ∪ cast+attn1 ∪ hist — one dispatch (r13 ordering)
  phase1_kernel<<<PH1_BLKS, 256, 0, stream>>>(
      W1, b1, c1w, c1b, W2, att_s2, att_d2, b2, c2w, c2b, M1t, p1, bias1p,
      M2t, p2, bias2p, x, x_bf, as1, ad1v, ed1, ed2, deg1, deg2, rank1, rank2);

  scanA12_kernel<<<NB1 + NB2, 256, 0, stream>>>(deg1, deg2, part12);
  scanC12_kernel<<<NB1 + NB2, 256, 0, stream>>>(deg1, deg2, part12, offs1,
                                                offs2);
  scatter1_kernel<<<(E1 + 255) / 256, 256, 0, stream>>>(
      es1, ed1, E1, offs1, rank1, as1, ad1v, csr_src1, csr_w1);
  gather1_kernel<<<(N1 + 3) / 4, 256, 0, stream>>>(x_bf, csr_src1, csr_w1,
                                                   offs1, z1);
  // hid1 = z1 @ M1 + bias1'  (128x128-tile GEMM)
  mm128_bf16_kernel<<<dim3(2, (N1 + 127) / 128), 256, 0, stream>>>(
      z1, M1t, bias1p, hid1, N1, 256, 512);

  attn2_kernel<<<(N1 + 7) / 8, 256, 0, stream>>>(hid1, p2, as2, ad2v);
  scatter2_kernel<<<(E2 + 255) / 256, 256, 0, stream>>>(
      es2, ed2, E2, offs2, rank2, as2, ad2v, csr_src2, csr_w2);
  gather2_kernel<<<(N2 + 3) / 4, 256, 0, stream>>>(hid1, csr_src2, csr_w2,
                                                   offs2, z2);
  mm_bf16_kernel<true, false><<<dim3(2, (N2 + 127) / 128), 256, 0, stream>>>(
      z2, M2t, bias2p, out, N2, 128, 256);
}